// Round 14
// baseline (780.334 us; speedup 1.0000x reference)
//
#include <hip/hip_runtime.h>
#include <math.h>

// ---------------------------------------------------------------------------
// STaRNet forward, fully fused fp32 pipeline.
//
//  k_prep : fold spatial convs+BN+wf-conv+BN into M(50x22)+biasf(50);
//           fold temporal BN into COMPACT conv taps wtf[50][336] + bt[450].
//  k_main : R13 (measured ~244us): 2-phase g-split, xt[25][320] (31.25KB,
//           5 blocks/CU), v4f conv + y-accum, accumulators in registers.
//  k_eig  : R5 structure (measured 471us) + EXACT ROTATION SKIP: a pair
//           with |apq| <= 1e-5*sqrt(app*aqq) gets (c,s)=(1,0) -> identity
//           rotation -> its col/row LDS RMW is skipped (wave-uniform flag,
//           barriers unconditional).  Late sweeps collapse to params+
//           barriers.  16 waves x 2 pairs, odd-pitch A/V, 2 barriers/round,
//           6 sweeps; syrk 4x4 on 256 thr; log-eig recon; triu -> FC.
// ---------------------------------------------------------------------------

typedef __attribute__((ext_vector_type(4))) float v4f;

#define NSWEEP 6
#define JSKIP  1e-5f

// ws float offsets
#define WS_M      0         // 50*22
#define WS_BIASF  1100      // 50
#define WS_WTF    1152      // 50*336 compact taps
#define WS_BT     17952     // 450
#define WS_HPART  18432     // 512
#define WS_Y      32768     // 128*64*1001

__global__ void k_prep(
    const float* __restrict__ ws0, const float* __restrict__ ws1, const float* __restrict__ ws2,
    const float* __restrict__ bsg, const float* __restrict__ bsb, const float* __restrict__ bsm, const float* __restrict__ bsv,
    const float* __restrict__ wf,
    const float* __restrict__ bfg, const float* __restrict__ bfb, const float* __restrict__ bfm, const float* __restrict__ bfv,
    const float* __restrict__ wt0, const float* __restrict__ wt1, const float* __restrict__ wt2,
    const float* __restrict__ btg, const float* __restrict__ btb, const float* __restrict__ btm, const float* __restrict__ btv,
    float* __restrict__ wsf)
{
    int tid = threadIdx.x;
    if (tid < 450) {
        int c = tid;
        int i = c / 150, o = c % 150;
        int g = o / 3,   jr = o % 3;
        int k = (i == 0) ? 64 : ((i == 1) ? 32 : 16);
        float ga = btg[i*150 + o], bb = btb[i*150 + o];
        float mm = btm[i*150 + o], vv = btv[i*150 + o];
        float s = ga * rsqrtf(vv + 1e-5f);
        wsf[WS_BT + c] = bb - s * mm;
        int base = g*336 + ((i == 0) ? jr*64 : (i == 1) ? 192 + jr*32 : 288 + jr*16);
        const float* wsrc = (i == 0) ? wt0 : ((i == 1) ? wt1 : wt2);
        float* dst = wsf + WS_WTF + base;
        for (int t = 0; t < k; ++t) dst[t] = s * wsrc[o*k + t];
    }
    if (tid < 50) {
        int f = tid;
        float sf = bfg[f] * rsqrtf(bfv[f] + 1e-5f);
        float row[22];
        for (int c = 0; c < 22; ++c) row[c] = 0.f;
        float bacc = 0.f;
        for (int j = 0; j < 60; ++j) {
            int i, k, j0; const float* wsp;
            if (j < 22)      { i = 0; k = 1; j0 = j;      wsp = ws0; }
            else if (j < 42) { i = 1; k = 3; j0 = j - 22; wsp = ws1; }
            else             { i = 2; k = 5; j0 = j - 42; wsp = ws2; }
            float si = bsg[i] * rsqrtf(bsv[i] + 1e-5f);
            float bi = bsb[i] - si * bsm[i];
            float wfj = wf[f*60 + j];
            for (int d = 0; d < k; ++d) row[j0 + d] += wfj * si * wsp[d];
            bacc += wfj * bi;
        }
        for (int c = 0; c < 22; ++c) wsf[WS_M + f*22 + c] = sf * row[c];
        wsf[WS_BIASF + f] = sf * (bacc - bfm[f]) + bfb[f];
    }
}

// ---------------------------------------------------------------------------
__global__ __launch_bounds__(256) void k_main(
    const float* __restrict__ x, const float* __restrict__ wsf,
    const float* __restrict__ Wmap, float* __restrict__ y,
    float* __restrict__ hpart)
{
    const int b    = blockIdx.x >> 2;
    const int tile = blockIdx.x & 3;
    const int t0   = tile * 256;
    const int tid  = threadIdx.x;

    __shared__ float xt[25][320];   // xf half-tile (31.25 KB -> 5 blocks/CU)
    __shared__ float wred[4];

    const float* Mg    = wsf + WS_M;
    const float* biasf = wsf + WS_BIASF;
    const float* wtf   = wsf + WS_WTF;
    const float* bt    = wsf + WS_BT;

    const int t = t0 + tid;
    const bool act = (t <= 1000);
    v4f yv4[16];
    #pragma unroll
    for (int m = 0; m < 16; ++m) yv4[m] = (v4f){0.f, 0.f, 0.f, 0.f};
    float hsq = 0.f;

    for (int ph = 0; ph < 2; ++ph) {
        const int gbase = 25 * ph;
        if (ph) __syncthreads();   // prev-phase conv reads done before restage

        // ---- stage xf rows [gbase, gbase+25) ----
        for (int col = tid; col < 320; col += 256) {
            int tx = t0 + col - 32;
            if (tx >= 0 && tx < 1000) {
                float xv[22];
                #pragma unroll
                for (int c = 0; c < 22; ++c) xv[c] = x[(b*22 + c)*1000 + tx];
                for (int gl = 0; gl < 25; ++gl) {
                    int g = gbase + gl;
                    float a = biasf[g];
                    #pragma unroll
                    for (int c = 0; c < 22; ++c) a += Mg[g*22 + c] * xv[c];
                    xt[gl][col] = a;
                }
            } else {
                for (int gl = 0; gl < 25; ++gl) xt[gl][col] = 0.f;
            }
        }
        __syncthreads();

        // ---- conv + y-accum for these 25 g ----
        if (act) {
            for (int gl = 0; gl < 25; ++gl) {
                const int g = gbase + gl;
                const float* xb = &xt[gl][tid];
                const float* wg = wtf + g * 336;
                v4f h4[9];
                #pragma unroll
                for (int j = 0; j < 9; ++j) h4[j] = (v4f){0.f, 0.f, 0.f, 0.f};
                #pragma unroll
                for (int tau = 0; tau < 64; tau += 4) {
                    v4f xv = (v4f){xb[tau], xb[tau+1], xb[tau+2], xb[tau+3]};
                    h4[0] += (*(const v4f*)(wg + tau))       * xv;
                    h4[1] += (*(const v4f*)(wg + 64 + tau))  * xv;
                    h4[2] += (*(const v4f*)(wg + 128 + tau)) * xv;
                    if (tau >= 16 && tau < 48) {
                        int u = tau - 16;
                        h4[3] += (*(const v4f*)(wg + 192 + u)) * xv;
                        h4[4] += (*(const v4f*)(wg + 224 + u)) * xv;
                        h4[5] += (*(const v4f*)(wg + 256 + u)) * xv;
                    }
                    if (tau >= 24 && tau < 40) {
                        int u = tau - 24;
                        h4[6] += (*(const v4f*)(wg + 288 + u)) * xv;
                        h4[7] += (*(const v4f*)(wg + 304 + u)) * xv;
                        h4[8] += (*(const v4f*)(wg + 320 + u)) * xv;
                    }
                }
                #pragma unroll
                for (int j = 0; j < 9; ++j) {
                    int c = (j < 3) ? (3*g + j)
                          : (j < 6) ? (150 + 3*g + (j - 3))
                                    : (300 + 3*g + (j - 6));
                    float hv = (h4[j].x + h4[j].y) + (h4[j].z + h4[j].w) + bt[c];
                    hsq += hv * hv;
                    const v4f* wr4 = (const v4f*)(Wmap + c * 64);  // wave-uniform
                    v4f hv4 = (v4f){hv, hv, hv, hv};
                    #pragma unroll
                    for (int m = 0; m < 16; ++m) yv4[m] += wr4[m] * hv4;
                }
            }
        }
    }

    if (act) {
        #pragma unroll
        for (int k = 0; k < 16; ++k) {
            y[(b*64 + 4*k)*1001 + t]     = yv4[k].x;
            y[(b*64 + 4*k + 1)*1001 + t] = yv4[k].y;
            y[(b*64 + 4*k + 2)*1001 + t] = yv4[k].z;
            y[(b*64 + 4*k + 3)*1001 + t] = yv4[k].w;
        }
    }

    for (int off = 32; off > 0; off >>= 1) hsq += __shfl_down(hsq, off, 64);
    int wid = tid >> 6, lane = tid & 63;
    if (lane == 0) wred[wid] = hsq;
    __syncthreads();
    if (tid == 0) hpart[blockIdx.x] = wred[0] + wred[1] + wred[2] + wred[3];
}

// ---------------------------------------------------------------------------
// pair schedule: round rr, pair j: j==0 -> (63, rr); else
// p=(rr+j)%63, q=(rr+63-j)%63. All pairs disjoint within a round.
__device__ __forceinline__ void pair_pq(int rr, int j, int& p, int& q) {
    if (j == 0) { p = 63; q = rr; }
    else {
        int a = rr + j;       if (a >= 63) a -= 63;
        int c = rr + 63 - j;  if (c >= 63) c -= 63;
        p = a; q = c;
    }
}

union SMu {
    float yt[64][129];                               // syrk staging (33024 B)
    struct { float A[64][65]; float V[64][65]; } j;  // Jacobi (33280 B)
};

__global__ __launch_bounds__(1024) void k_eig(
    const float* __restrict__ y, const float* __restrict__ hpart,
    const float* __restrict__ fcw, const float* __restrict__ fcb,
    float* __restrict__ out)
{
    const int b    = blockIdx.x;
    const int tid  = threadIdx.x;
    const int w    = tid >> 6;     // wave 0..15
    const int lane = tid & 63;

    __shared__ SMu U;
    __shared__ float le[64];
    __shared__ float wred2[16];

    // ---- syrk: acc = y y^T; staging by all 16 waves, MACs on first 256 ----
    const int mg = tid >> 4, ng = tid & 15;       // valid for tid<256
    const int m0 = mg * 4,  n0 = ng * 4;
    float acc[16];
    #pragma unroll
    for (int i = 0; i < 16; ++i) acc[i] = 0.f;
    for (int tile = 0; tile < 8; ++tile) {
        for (int idx = tid; idx < 64*128; idx += 1024) {
            int row = idx >> 7, col = idx & 127;
            int tg = tile * 128 + col;
            U.yt[row][col] = (tg <= 1000) ? y[(b*64 + row)*1001 + tg] : 0.f;
        }
        __syncthreads();
        if (tid < 256) {
            for (int tt = 0; tt < 128; ++tt) {
                float ym[4], yn[4];
                #pragma unroll
                for (int i = 0; i < 4; ++i) ym[i] = U.yt[m0 + i][tt];
                #pragma unroll
                for (int j = 0; j < 4; ++j) yn[j] = U.yt[n0 + j][tt];
                #pragma unroll
                for (int i = 0; i < 4; ++i)
                    #pragma unroll
                    for (int j = 0; j < 4; ++j) acc[i*4 + j] += ym[i] * yn[j];
            }
        }
        __syncthreads();
    }
    if (tid < 256) {
        float hs = hpart[b*4] + hpart[b*4+1] + hpart[b*4+2] + hpart[b*4+3];
        float mu = hs / (999.f * 450.f);
        #pragma unroll
        for (int i = 0; i < 4; ++i)
            #pragma unroll
            for (int j = 0; j < 4; ++j) {
                int mm = m0 + i, nn = n0 + j;
                U.j.A[mm][nn] = acc[i*4 + j] * (0.95f / 999.f)
                              + ((mm == nn) ? 0.05f * mu : 0.f);
                U.j.V[mm][nn] = (mm == nn) ? 1.f : 0.f;
            }
    }
    __syncthreads();

    // ---- parallel cyclic Jacobi: 16 waves x 2 pairs, conflict-free b32,
    //      exact rotation-skip (identity rotations skip their LDS RMW) ----
    for (int sweep = 0; sweep < NSWEEP; ++sweep)
    for (int rr = 0; rr < 63; ++rr) {
        float cp, sp;
        {
            int jj = w + ((lane & 1) << 4);
            int p, q; pair_pq(rr, jj, p, q);
            float app = U.j.A[p][p], aqq = U.j.A[q][q], apq = U.j.A[p][q];
            // diag of a PSD matrix under rotation congruence stays >= lam_min > 0
            bool z = (fabsf(apq) <= JSKIP * sqrtf(app * aqq));
            float apqs = z ? 1.f : apq;
            float tau = (aqq - app) * __builtin_amdgcn_rcpf(2.f * apqs);
            float tt = copysignf(1.f, tau) / (fabsf(tau) + sqrtf(1.f + tau*tau));
            float c = rsqrtf(1.f + tt*tt);
            float s = tt * c;
            cp = z ? 1.f : c;
            sp = z ? 0.f : s;
        }
        float c0 = __shfl(cp, 0, 64), s0 = __shfl(sp, 0, 64);
        float c1 = __shfl(cp, 1, 64), s1 = __shfl(sp, 1, 64);
        const bool do0 = (s0 != 0.f);   // wave-uniform
        const bool do1 = (s1 != 0.f);
        int p0, q0, p1, q1;
        pair_pq(rr, w,      p0, q0);
        pair_pq(rr, w + 16, p1, q1);

        // col phase: batched loads, rotate, batched stores (A and V)
        if (do0) {
            float a0p = U.j.A[lane][p0], a0q = U.j.A[lane][q0];
            float v0p = U.j.V[lane][p0], v0q = U.j.V[lane][q0];
            U.j.A[lane][p0] = c0*a0p - s0*a0q;
            U.j.A[lane][q0] = s0*a0p + c0*a0q;
            U.j.V[lane][p0] = c0*v0p - s0*v0q;
            U.j.V[lane][q0] = s0*v0p + c0*v0q;
        }
        if (do1) {
            float a1p = U.j.A[lane][p1], a1q = U.j.A[lane][q1];
            float v1p = U.j.V[lane][p1], v1q = U.j.V[lane][q1];
            U.j.A[lane][p1] = c1*a1p - s1*a1q;
            U.j.A[lane][q1] = s1*a1p + c1*a1q;
            U.j.V[lane][p1] = c1*v1p - s1*v1q;
            U.j.V[lane][q1] = s1*v1p + c1*v1q;
        }
        __syncthreads();

        // row phase (A only)
        if (do0) {
            float r0p = U.j.A[p0][lane], r0q = U.j.A[q0][lane];
            U.j.A[p0][lane] = c0*r0p - s0*r0q;
            U.j.A[q0][lane] = s0*r0p + c0*r0q;
        }
        if (do1) {
            float r1p = U.j.A[p1][lane], r1q = U.j.A[q1][lane];
            U.j.A[p1][lane] = c1*r1p - s1*r1q;
            U.j.A[q1][lane] = s1*r1p + c1*r1q;
        }
        __syncthreads();
    }

    // ---- log-eig reconstruction + FC (first 256 threads) ----
    if (tid < 64) le[tid] = logf(fmaxf(U.j.A[tid][tid], 1e-6f));
    __syncthreads();

    if (tid < 256) {
        float lm[16];
        #pragma unroll
        for (int i = 0; i < 16; ++i) lm[i] = 0.f;
        for (int k = 0; k < 64; ++k) {
            float l = le[k];
            float vm[4], vn[4];
            #pragma unroll
            for (int i = 0; i < 4; ++i) vm[i] = U.j.V[m0 + i][k] * l;
            #pragma unroll
            for (int j = 0; j < 4; ++j) vn[j] = U.j.V[n0 + j][k];
            #pragma unroll
            for (int i = 0; i < 4; ++i)
                #pragma unroll
                for (int j = 0; j < 4; ++j) lm[i*4 + j] += vm[i] * vn[j];
        }

        float fa[4];
        #pragma unroll
        for (int o = 0; o < 4; ++o) fa[o] = 0.f;
        #pragma unroll
        for (int i = 0; i < 4; ++i)
            #pragma unroll
            for (int j = 0; j < 4; ++j) {
                int gi = m0 + i, gj = n0 + j;
                if (gi <= gj) {
                    int p = gi*64 - (gi*(gi-1))/2 + (gj - gi);
                    float lv = lm[i*4 + j];
                    #pragma unroll
                    for (int o = 0; o < 4; ++o) fa[o] += lv * fcw[o*2080 + p];
                }
            }

        #pragma unroll
        for (int o = 0; o < 4; ++o)
            for (int off = 32; off > 0; off >>= 1)
                fa[o] += __shfl_down(fa[o], off, 64);
        if (lane == 0) {
            #pragma unroll
            for (int o = 0; o < 4; ++o) wred2[w*4 + o] = fa[o];
        }
    }
    __syncthreads();
    if (tid < 4)
        out[b*4 + tid] = wred2[tid] + wred2[4 + tid] + wred2[8 + tid]
                       + wred2[12 + tid] + fcb[tid];
}

// ---------------------------------------------------------------------------
extern "C" void kernel_launch(void* const* d_in, const int* in_sizes, int n_in,
                              void* d_out, int out_size, void* d_ws, size_t ws_size,
                              hipStream_t stream) {
    (void)in_sizes; (void)n_in; (void)out_size; (void)ws_size;
    const float* x   = (const float*)d_in[0];
    const float* ws0 = (const float*)d_in[1];
    const float* ws1 = (const float*)d_in[2];
    const float* ws2 = (const float*)d_in[3];
    const float* bsg = (const float*)d_in[4];
    const float* bsb = (const float*)d_in[5];
    const float* bsm = (const float*)d_in[6];
    const float* bsv = (const float*)d_in[7];
    const float* wf  = (const float*)d_in[8];
    const float* bfg = (const float*)d_in[9];
    const float* bfb = (const float*)d_in[10];
    const float* bfm = (const float*)d_in[11];
    const float* bfv = (const float*)d_in[12];
    const float* wt0 = (const float*)d_in[13];
    const float* wt1 = (const float*)d_in[14];
    const float* wt2 = (const float*)d_in[15];
    const float* btg = (const float*)d_in[16];
    const float* btb = (const float*)d_in[17];
    const float* btm = (const float*)d_in[18];
    const float* btv = (const float*)d_in[19];
    const float* Wm  = (const float*)d_in[20];
    const float* fcw = (const float*)d_in[21];
    const float* fcb = (const float*)d_in[22];

    float* wsf   = (float*)d_ws;
    float* yb    = wsf + WS_Y;
    float* hpart = wsf + WS_HPART;

    k_prep<<<1, 512, 0, stream>>>(ws0, ws1, ws2, bsg, bsb, bsm, bsv,
                                  wf, bfg, bfb, bfm, bfv,
                                  wt0, wt1, wt2, btg, btb, btm, btv, wsf);
    k_main<<<512, 256, 0, stream>>>(x, wsf, Wm, yb, hpart);
    k_eig<<<128, 1024, 0, stream>>>(yb, hpart, fcw, fcb, (float*)d_out);
}

// Round 15
// 772.163 us; speedup vs baseline: 1.0106x; 1.0106x over previous
//
#include <hip/hip_runtime.h>
#include <math.h>

// ---------------------------------------------------------------------------
// STaRNet forward, fully fused fp32 pipeline.
//
//  k_prep : fold spatial convs+BN+wf-conv+BN into M(50x22)+biasf(50);
//           fold temporal BN into COMPACT conv taps wtf[50][336] + bt[450].
//  k_main : R13 (measured ~244us): 2-phase g-split, xt[25][320] (31.25KB,
//           5 blocks/CU), v4f conv + y-accum, accumulators in registers.
//  k_eig  : R5 structure, re-balanced to 8 WAVES x 4 PAIRS (512 threads).
//           R14 lesson: rotation-skip branches broke LDS batching (+48us).
//           R15 theory: per-CU LDS work/round is fixed (32 pairs), but the
//           2 barriers/round sync 16 lockstep waves -> skew + simultaneous
//           param-chain stalls dominate (measured 2580 cyc/round vs ~900
//           issue floor).  8 waves halve barrier skew; 4 independent
//           pair-chains per wave double ILP.  Sweeps stay 6.
// ---------------------------------------------------------------------------

typedef __attribute__((ext_vector_type(4))) float v4f;

#define NSWEEP 6

// ws float offsets
#define WS_M      0         // 50*22
#define WS_BIASF  1100      // 50
#define WS_WTF    1152      // 50*336 compact taps
#define WS_BT     17952     // 450
#define WS_HPART  18432     // 512
#define WS_Y      32768     // 128*64*1001

__global__ void k_prep(
    const float* __restrict__ ws0, const float* __restrict__ ws1, const float* __restrict__ ws2,
    const float* __restrict__ bsg, const float* __restrict__ bsb, const float* __restrict__ bsm, const float* __restrict__ bsv,
    const float* __restrict__ wf,
    const float* __restrict__ bfg, const float* __restrict__ bfb, const float* __restrict__ bfm, const float* __restrict__ bfv,
    const float* __restrict__ wt0, const float* __restrict__ wt1, const float* __restrict__ wt2,
    const float* __restrict__ btg, const float* __restrict__ btb, const float* __restrict__ btm, const float* __restrict__ btv,
    float* __restrict__ wsf)
{
    int tid = threadIdx.x;
    if (tid < 450) {
        int c = tid;
        int i = c / 150, o = c % 150;
        int g = o / 3,   jr = o % 3;
        int k = (i == 0) ? 64 : ((i == 1) ? 32 : 16);
        float ga = btg[i*150 + o], bb = btb[i*150 + o];
        float mm = btm[i*150 + o], vv = btv[i*150 + o];
        float s = ga * rsqrtf(vv + 1e-5f);
        wsf[WS_BT + c] = bb - s * mm;
        int base = g*336 + ((i == 0) ? jr*64 : (i == 1) ? 192 + jr*32 : 288 + jr*16);
        const float* wsrc = (i == 0) ? wt0 : ((i == 1) ? wt1 : wt2);
        float* dst = wsf + WS_WTF + base;
        for (int t = 0; t < k; ++t) dst[t] = s * wsrc[o*k + t];
    }
    if (tid < 50) {
        int f = tid;
        float sf = bfg[f] * rsqrtf(bfv[f] + 1e-5f);
        float row[22];
        for (int c = 0; c < 22; ++c) row[c] = 0.f;
        float bacc = 0.f;
        for (int j = 0; j < 60; ++j) {
            int i, k, j0; const float* wsp;
            if (j < 22)      { i = 0; k = 1; j0 = j;      wsp = ws0; }
            else if (j < 42) { i = 1; k = 3; j0 = j - 22; wsp = ws1; }
            else             { i = 2; k = 5; j0 = j - 42; wsp = ws2; }
            float si = bsg[i] * rsqrtf(bsv[i] + 1e-5f);
            float bi = bsb[i] - si * bsm[i];
            float wfj = wf[f*60 + j];
            for (int d = 0; d < k; ++d) row[j0 + d] += wfj * si * wsp[d];
            bacc += wfj * bi;
        }
        for (int c = 0; c < 22; ++c) wsf[WS_M + f*22 + c] = sf * row[c];
        wsf[WS_BIASF + f] = sf * (bacc - bfm[f]) + bfb[f];
    }
}

// ---------------------------------------------------------------------------
__global__ __launch_bounds__(256) void k_main(
    const float* __restrict__ x, const float* __restrict__ wsf,
    const float* __restrict__ Wmap, float* __restrict__ y,
    float* __restrict__ hpart)
{
    const int b    = blockIdx.x >> 2;
    const int tile = blockIdx.x & 3;
    const int t0   = tile * 256;
    const int tid  = threadIdx.x;

    __shared__ float xt[25][320];   // xf half-tile (31.25 KB -> 5 blocks/CU)
    __shared__ float wred[4];

    const float* Mg    = wsf + WS_M;
    const float* biasf = wsf + WS_BIASF;
    const float* wtf   = wsf + WS_WTF;
    const float* bt    = wsf + WS_BT;

    const int t = t0 + tid;
    const bool act = (t <= 1000);
    v4f yv4[16];
    #pragma unroll
    for (int m = 0; m < 16; ++m) yv4[m] = (v4f){0.f, 0.f, 0.f, 0.f};
    float hsq = 0.f;

    for (int ph = 0; ph < 2; ++ph) {
        const int gbase = 25 * ph;
        if (ph) __syncthreads();   // prev-phase conv reads done before restage

        // ---- stage xf rows [gbase, gbase+25) ----
        for (int col = tid; col < 320; col += 256) {
            int tx = t0 + col - 32;
            if (tx >= 0 && tx < 1000) {
                float xv[22];
                #pragma unroll
                for (int c = 0; c < 22; ++c) xv[c] = x[(b*22 + c)*1000 + tx];
                for (int gl = 0; gl < 25; ++gl) {
                    int g = gbase + gl;
                    float a = biasf[g];
                    #pragma unroll
                    for (int c = 0; c < 22; ++c) a += Mg[g*22 + c] * xv[c];
                    xt[gl][col] = a;
                }
            } else {
                for (int gl = 0; gl < 25; ++gl) xt[gl][col] = 0.f;
            }
        }
        __syncthreads();

        // ---- conv + y-accum for these 25 g ----
        if (act) {
            for (int gl = 0; gl < 25; ++gl) {
                const int g = gbase + gl;
                const float* xb = &xt[gl][tid];
                const float* wg = wtf + g * 336;
                v4f h4[9];
                #pragma unroll
                for (int j = 0; j < 9; ++j) h4[j] = (v4f){0.f, 0.f, 0.f, 0.f};
                #pragma unroll
                for (int tau = 0; tau < 64; tau += 4) {
                    v4f xv = (v4f){xb[tau], xb[tau+1], xb[tau+2], xb[tau+3]};
                    h4[0] += (*(const v4f*)(wg + tau))       * xv;
                    h4[1] += (*(const v4f*)(wg + 64 + tau))  * xv;
                    h4[2] += (*(const v4f*)(wg + 128 + tau)) * xv;
                    if (tau >= 16 && tau < 48) {
                        int u = tau - 16;
                        h4[3] += (*(const v4f*)(wg + 192 + u)) * xv;
                        h4[4] += (*(const v4f*)(wg + 224 + u)) * xv;
                        h4[5] += (*(const v4f*)(wg + 256 + u)) * xv;
                    }
                    if (tau >= 24 && tau < 40) {
                        int u = tau - 24;
                        h4[6] += (*(const v4f*)(wg + 288 + u)) * xv;
                        h4[7] += (*(const v4f*)(wg + 304 + u)) * xv;
                        h4[8] += (*(const v4f*)(wg + 320 + u)) * xv;
                    }
                }
                #pragma unroll
                for (int j = 0; j < 9; ++j) {
                    int c = (j < 3) ? (3*g + j)
                          : (j < 6) ? (150 + 3*g + (j - 3))
                                    : (300 + 3*g + (j - 6));
                    float hv = (h4[j].x + h4[j].y) + (h4[j].z + h4[j].w) + bt[c];
                    hsq += hv * hv;
                    const v4f* wr4 = (const v4f*)(Wmap + c * 64);  // wave-uniform
                    v4f hv4 = (v4f){hv, hv, hv, hv};
                    #pragma unroll
                    for (int m = 0; m < 16; ++m) yv4[m] += wr4[m] * hv4;
                }
            }
        }
    }

    if (act) {
        #pragma unroll
        for (int k = 0; k < 16; ++k) {
            y[(b*64 + 4*k)*1001 + t]     = yv4[k].x;
            y[(b*64 + 4*k + 1)*1001 + t] = yv4[k].y;
            y[(b*64 + 4*k + 2)*1001 + t] = yv4[k].z;
            y[(b*64 + 4*k + 3)*1001 + t] = yv4[k].w;
        }
    }

    for (int off = 32; off > 0; off >>= 1) hsq += __shfl_down(hsq, off, 64);
    int wid = tid >> 6, lane = tid & 63;
    if (lane == 0) wred[wid] = hsq;
    __syncthreads();
    if (tid == 0) hpart[blockIdx.x] = wred[0] + wred[1] + wred[2] + wred[3];
}

// ---------------------------------------------------------------------------
// pair schedule: round rr, pair j: j==0 -> (63, rr); else
// p=(rr+j)%63, q=(rr+63-j)%63. All pairs disjoint within a round.
__device__ __forceinline__ void pair_pq(int rr, int j, int& p, int& q) {
    if (j == 0) { p = 63; q = rr; }
    else {
        int a = rr + j;       if (a >= 63) a -= 63;
        int c = rr + 63 - j;  if (c >= 63) c -= 63;
        p = a; q = c;
    }
}

union SMu {
    float yt[64][129];                               // syrk staging (33024 B)
    struct { float A[64][65]; float V[64][65]; } j;  // Jacobi (33280 B)
};

__global__ __launch_bounds__(512) void k_eig(
    const float* __restrict__ y, const float* __restrict__ hpart,
    const float* __restrict__ fcw, const float* __restrict__ fcb,
    float* __restrict__ out)
{
    const int b    = blockIdx.x;
    const int tid  = threadIdx.x;
    const int w    = tid >> 6;     // wave 0..7
    const int lane = tid & 63;

    __shared__ SMu U;
    __shared__ float le[64];
    __shared__ float wred2[16];

    // ---- syrk: acc = y y^T; staging by all 8 waves, MACs on first 256 ----
    const int mg = tid >> 4, ng = tid & 15;       // valid for tid<256
    const int m0 = mg * 4,  n0 = ng * 4;
    float acc[16];
    #pragma unroll
    for (int i = 0; i < 16; ++i) acc[i] = 0.f;
    for (int tile = 0; tile < 8; ++tile) {
        for (int idx = tid; idx < 64*128; idx += 512) {
            int row = idx >> 7, col = idx & 127;
            int tg = tile * 128 + col;
            U.yt[row][col] = (tg <= 1000) ? y[(b*64 + row)*1001 + tg] : 0.f;
        }
        __syncthreads();
        if (tid < 256) {
            for (int tt = 0; tt < 128; ++tt) {
                float ym[4], yn[4];
                #pragma unroll
                for (int i = 0; i < 4; ++i) ym[i] = U.yt[m0 + i][tt];
                #pragma unroll
                for (int j = 0; j < 4; ++j) yn[j] = U.yt[n0 + j][tt];
                #pragma unroll
                for (int i = 0; i < 4; ++i)
                    #pragma unroll
                    for (int j = 0; j < 4; ++j) acc[i*4 + j] += ym[i] * yn[j];
            }
        }
        __syncthreads();
    }
    if (tid < 256) {
        float hs = hpart[b*4] + hpart[b*4+1] + hpart[b*4+2] + hpart[b*4+3];
        float mu = hs / (999.f * 450.f);
        #pragma unroll
        for (int i = 0; i < 4; ++i)
            #pragma unroll
            for (int j = 0; j < 4; ++j) {
                int mm = m0 + i, nn = n0 + j;
                U.j.A[mm][nn] = acc[i*4 + j] * (0.95f / 999.f)
                              + ((mm == nn) ? 0.05f * mu : 0.f);
                U.j.V[mm][nn] = (mm == nn) ? 1.f : 0.f;
            }
    }
    __syncthreads();

    // ---- parallel cyclic Jacobi: 8 waves x 4 pairs, conflict-free b32 ----
    // Wave w owns pairs {w, w+8, w+16, w+24}.  Params: lane computes (c,s)
    // of pair w + 8*(lane&3); shfl lanes 0..3 broadcast.  Col phase: all 16
    // col loads batched (4 independent pair-chains of ILP), rotate, store;
    // barrier; row phase (A only); barrier.
    for (int sweep = 0; sweep < NSWEEP; ++sweep)
    for (int rr = 0; rr < 63; ++rr) {
        float cp, sp;
        {
            int jj = w + ((lane & 3) << 3);
            int p, q; pair_pq(rr, jj, p, q);
            float app = U.j.A[p][p], aqq = U.j.A[q][q], apq = U.j.A[p][q];
            bool z = (fabsf(apq) <= 1e-30f);
            float apqs = z ? 1.f : apq;
            float tau = (aqq - app) * __builtin_amdgcn_rcpf(2.f * apqs);
            float tt = copysignf(1.f, tau) / (fabsf(tau) + sqrtf(1.f + tau*tau));
            float c = rsqrtf(1.f + tt*tt);
            float s = tt * c;
            cp = z ? 1.f : c;
            sp = z ? 0.f : s;
        }
        float cr[4], sr[4];
        int pA[4], qA[4];
        #pragma unroll
        for (int k = 0; k < 4; ++k) {
            cr[k] = __shfl(cp, k, 64);
            sr[k] = __shfl(sp, k, 64);
            pair_pq(rr, w + 8*k, pA[k], qA[k]);
        }

        // col phase: batched loads (A and V for all 4 pairs), rotate, store
        float ap[4], aq[4], vp[4], vq[4];
        #pragma unroll
        for (int k = 0; k < 4; ++k) {
            ap[k] = U.j.A[lane][pA[k]];
            aq[k] = U.j.A[lane][qA[k]];
            vp[k] = U.j.V[lane][pA[k]];
            vq[k] = U.j.V[lane][qA[k]];
        }
        #pragma unroll
        for (int k = 0; k < 4; ++k) {
            float c = cr[k], s = sr[k];
            U.j.A[lane][pA[k]] = c*ap[k] - s*aq[k];
            U.j.A[lane][qA[k]] = s*ap[k] + c*aq[k];
            U.j.V[lane][pA[k]] = c*vp[k] - s*vq[k];
            U.j.V[lane][qA[k]] = s*vp[k] + c*vq[k];
        }
        __syncthreads();

        // row phase (A only), batched
        float rp[4], rq[4];
        #pragma unroll
        for (int k = 0; k < 4; ++k) {
            rp[k] = U.j.A[pA[k]][lane];
            rq[k] = U.j.A[qA[k]][lane];
        }
        #pragma unroll
        for (int k = 0; k < 4; ++k) {
            float c = cr[k], s = sr[k];
            U.j.A[pA[k]][lane] = c*rp[k] - s*rq[k];
            U.j.A[qA[k]][lane] = s*rp[k] + c*rq[k];
        }
        __syncthreads();
    }

    // ---- log-eig reconstruction + FC (first 256 threads) ----
    if (tid < 64) le[tid] = logf(fmaxf(U.j.A[tid][tid], 1e-6f));
    __syncthreads();

    if (tid < 256) {
        float lm[16];
        #pragma unroll
        for (int i = 0; i < 16; ++i) lm[i] = 0.f;
        for (int k = 0; k < 64; ++k) {
            float l = le[k];
            float vm[4], vn[4];
            #pragma unroll
            for (int i = 0; i < 4; ++i) vm[i] = U.j.V[m0 + i][k] * l;
            #pragma unroll
            for (int j = 0; j < 4; ++j) vn[j] = U.j.V[n0 + j][k];
            #pragma unroll
            for (int i = 0; i < 4; ++i)
                #pragma unroll
                for (int j = 0; j < 4; ++j) lm[i*4 + j] += vm[i] * vn[j];
        }

        float fa[4];
        #pragma unroll
        for (int o = 0; o < 4; ++o) fa[o] = 0.f;
        #pragma unroll
        for (int i = 0; i < 4; ++i)
            #pragma unroll
            for (int j = 0; j < 4; ++j) {
                int gi = m0 + i, gj = n0 + j;
                if (gi <= gj) {
                    int p = gi*64 - (gi*(gi-1))/2 + (gj - gi);
                    float lv = lm[i*4 + j];
                    #pragma unroll
                    for (int o = 0; o < 4; ++o) fa[o] += lv * fcw[o*2080 + p];
                }
            }

        #pragma unroll
        for (int o = 0; o < 4; ++o)
            for (int off = 32; off > 0; off >>= 1)
                fa[o] += __shfl_down(fa[o], off, 64);
        if (lane == 0) {
            #pragma unroll
            for (int o = 0; o < 4; ++o) wred2[w*4 + o] = fa[o];
        }
    }
    __syncthreads();
    if (tid < 4)
        out[b*4 + tid] = wred2[tid] + wred2[4 + tid] + wred2[8 + tid]
                       + wred2[12 + tid] + fcb[tid];
}

// ---------------------------------------------------------------------------
extern "C" void kernel_launch(void* const* d_in, const int* in_sizes, int n_in,
                              void* d_out, int out_size, void* d_ws, size_t ws_size,
                              hipStream_t stream) {
    (void)in_sizes; (void)n_in; (void)out_size; (void)ws_size;
    const float* x   = (const float*)d_in[0];
    const float* ws0 = (const float*)d_in[1];
    const float* ws1 = (const float*)d_in[2];
    const float* ws2 = (const float*)d_in[3];
    const float* bsg = (const float*)d_in[4];
    const float* bsb = (const float*)d_in[5];
    const float* bsm = (const float*)d_in[6];
    const float* bsv = (const float*)d_in[7];
    const float* wf  = (const float*)d_in[8];
    const float* bfg = (const float*)d_in[9];
    const float* bfb = (const float*)d_in[10];
    const float* bfm = (const float*)d_in[11];
    const float* bfv = (const float*)d_in[12];
    const float* wt0 = (const float*)d_in[13];
    const float* wt1 = (const float*)d_in[14];
    const float* wt2 = (const float*)d_in[15];
    const float* btg = (const float*)d_in[16];
    const float* btb = (const float*)d_in[17];
    const float* btm = (const float*)d_in[18];
    const float* btv = (const float*)d_in[19];
    const float* Wm  = (const float*)d_in[20];
    const float* fcw = (const float*)d_in[21];
    const float* fcb = (const float*)d_in[22];

    float* wsf   = (float*)d_ws;
    float* yb    = wsf + WS_Y;
    float* hpart = wsf + WS_HPART;

    k_prep<<<1, 512, 0, stream>>>(ws0, ws1, ws2, bsg, bsb, bsm, bsv,
                                  wf, bfg, bfb, bfm, bfv,
                                  wt0, wt1, wt2, btg, btb, btm, btv, wsf);
    k_main<<<512, 256, 0, stream>>>(x, wsf, Wm, yb, hpart);
    k_eig<<<128, 512, 0, stream>>>(yb, hpart, fcw, fcb, (float*)d_out);
}

// Round 16
// 669.566 us; speedup vs baseline: 1.1654x; 1.1532x over previous
//
#include <hip/hip_runtime.h>
#include <math.h>

// ---------------------------------------------------------------------------
// STaRNet forward, fully fused fp32 pipeline.
//
//  k_prep : fold spatial convs+BN+wf-conv+BN into M(50x22)+biasf(50);
//           fold temporal BN into COMPACT conv taps wtf[50][336] + bt[450].
//  k_main : R13 (measured ~244us): 2-phase g-split, xt[25][320] (31.25KB,
//           5 blocks/CU), v4f conv + y-accum, accumulators in registers.
//  k_eig  : R12 structure verbatim (measured 471us twice; 16 waves x 2
//           pairs is the local optimum: 8x4=508, 4-wave=536, 1-wave=760,
//           skip-branches=519) with NSWEEP 6->5.  Error model from data:
//           absmax ~x2 per sweep removed (10->2.44e-4, 8->4.88e-4,
//           6->1.95e-3) => 5 sweeps ~3.9-7.8e-3 < 9.49e-3 threshold.
//           Rounds 378->315.
// ---------------------------------------------------------------------------

typedef __attribute__((ext_vector_type(4))) float v4f;

#define NSWEEP 5

// ws float offsets
#define WS_M      0         // 50*22
#define WS_BIASF  1100      // 50
#define WS_WTF    1152      // 50*336 compact taps
#define WS_BT     17952     // 450
#define WS_HPART  18432     // 512
#define WS_Y      32768     // 128*64*1001

__global__ void k_prep(
    const float* __restrict__ ws0, const float* __restrict__ ws1, const float* __restrict__ ws2,
    const float* __restrict__ bsg, const float* __restrict__ bsb, const float* __restrict__ bsm, const float* __restrict__ bsv,
    const float* __restrict__ wf,
    const float* __restrict__ bfg, const float* __restrict__ bfb, const float* __restrict__ bfm, const float* __restrict__ bfv,
    const float* __restrict__ wt0, const float* __restrict__ wt1, const float* __restrict__ wt2,
    const float* __restrict__ btg, const float* __restrict__ btb, const float* __restrict__ btm, const float* __restrict__ btv,
    float* __restrict__ wsf)
{
    int tid = threadIdx.x;
    if (tid < 450) {
        int c = tid;
        int i = c / 150, o = c % 150;
        int g = o / 3,   jr = o % 3;
        int k = (i == 0) ? 64 : ((i == 1) ? 32 : 16);
        float ga = btg[i*150 + o], bb = btb[i*150 + o];
        float mm = btm[i*150 + o], vv = btv[i*150 + o];
        float s = ga * rsqrtf(vv + 1e-5f);
        wsf[WS_BT + c] = bb - s * mm;
        int base = g*336 + ((i == 0) ? jr*64 : (i == 1) ? 192 + jr*32 : 288 + jr*16);
        const float* wsrc = (i == 0) ? wt0 : ((i == 1) ? wt1 : wt2);
        float* dst = wsf + WS_WTF + base;
        for (int t = 0; t < k; ++t) dst[t] = s * wsrc[o*k + t];
    }
    if (tid < 50) {
        int f = tid;
        float sf = bfg[f] * rsqrtf(bfv[f] + 1e-5f);
        float row[22];
        for (int c = 0; c < 22; ++c) row[c] = 0.f;
        float bacc = 0.f;
        for (int j = 0; j < 60; ++j) {
            int i, k, j0; const float* wsp;
            if (j < 22)      { i = 0; k = 1; j0 = j;      wsp = ws0; }
            else if (j < 42) { i = 1; k = 3; j0 = j - 22; wsp = ws1; }
            else             { i = 2; k = 5; j0 = j - 42; wsp = ws2; }
            float si = bsg[i] * rsqrtf(bsv[i] + 1e-5f);
            float bi = bsb[i] - si * bsm[i];
            float wfj = wf[f*60 + j];
            for (int d = 0; d < k; ++d) row[j0 + d] += wfj * si * wsp[d];
            bacc += wfj * bi;
        }
        for (int c = 0; c < 22; ++c) wsf[WS_M + f*22 + c] = sf * row[c];
        wsf[WS_BIASF + f] = sf * (bacc - bfm[f]) + bfb[f];
    }
}

// ---------------------------------------------------------------------------
__global__ __launch_bounds__(256) void k_main(
    const float* __restrict__ x, const float* __restrict__ wsf,
    const float* __restrict__ Wmap, float* __restrict__ y,
    float* __restrict__ hpart)
{
    const int b    = blockIdx.x >> 2;
    const int tile = blockIdx.x & 3;
    const int t0   = tile * 256;
    const int tid  = threadIdx.x;

    __shared__ float xt[25][320];   // xf half-tile (31.25 KB -> 5 blocks/CU)
    __shared__ float wred[4];

    const float* Mg    = wsf + WS_M;
    const float* biasf = wsf + WS_BIASF;
    const float* wtf   = wsf + WS_WTF;
    const float* bt    = wsf + WS_BT;

    const int t = t0 + tid;
    const bool act = (t <= 1000);
    v4f yv4[16];
    #pragma unroll
    for (int m = 0; m < 16; ++m) yv4[m] = (v4f){0.f, 0.f, 0.f, 0.f};
    float hsq = 0.f;

    for (int ph = 0; ph < 2; ++ph) {
        const int gbase = 25 * ph;
        if (ph) __syncthreads();   // prev-phase conv reads done before restage

        // ---- stage xf rows [gbase, gbase+25) ----
        for (int col = tid; col < 320; col += 256) {
            int tx = t0 + col - 32;
            if (tx >= 0 && tx < 1000) {
                float xv[22];
                #pragma unroll
                for (int c = 0; c < 22; ++c) xv[c] = x[(b*22 + c)*1000 + tx];
                for (int gl = 0; gl < 25; ++gl) {
                    int g = gbase + gl;
                    float a = biasf[g];
                    #pragma unroll
                    for (int c = 0; c < 22; ++c) a += Mg[g*22 + c] * xv[c];
                    xt[gl][col] = a;
                }
            } else {
                for (int gl = 0; gl < 25; ++gl) xt[gl][col] = 0.f;
            }
        }
        __syncthreads();

        // ---- conv + y-accum for these 25 g ----
        if (act) {
            for (int gl = 0; gl < 25; ++gl) {
                const int g = gbase + gl;
                const float* xb = &xt[gl][tid];
                const float* wg = wtf + g * 336;
                v4f h4[9];
                #pragma unroll
                for (int j = 0; j < 9; ++j) h4[j] = (v4f){0.f, 0.f, 0.f, 0.f};
                #pragma unroll
                for (int tau = 0; tau < 64; tau += 4) {
                    v4f xv = (v4f){xb[tau], xb[tau+1], xb[tau+2], xb[tau+3]};
                    h4[0] += (*(const v4f*)(wg + tau))       * xv;
                    h4[1] += (*(const v4f*)(wg + 64 + tau))  * xv;
                    h4[2] += (*(const v4f*)(wg + 128 + tau)) * xv;
                    if (tau >= 16 && tau < 48) {
                        int u = tau - 16;
                        h4[3] += (*(const v4f*)(wg + 192 + u)) * xv;
                        h4[4] += (*(const v4f*)(wg + 224 + u)) * xv;
                        h4[5] += (*(const v4f*)(wg + 256 + u)) * xv;
                    }
                    if (tau >= 24 && tau < 40) {
                        int u = tau - 24;
                        h4[6] += (*(const v4f*)(wg + 288 + u)) * xv;
                        h4[7] += (*(const v4f*)(wg + 304 + u)) * xv;
                        h4[8] += (*(const v4f*)(wg + 320 + u)) * xv;
                    }
                }
                #pragma unroll
                for (int j = 0; j < 9; ++j) {
                    int c = (j < 3) ? (3*g + j)
                          : (j < 6) ? (150 + 3*g + (j - 3))
                                    : (300 + 3*g + (j - 6));
                    float hv = (h4[j].x + h4[j].y) + (h4[j].z + h4[j].w) + bt[c];
                    hsq += hv * hv;
                    const v4f* wr4 = (const v4f*)(Wmap + c * 64);  // wave-uniform
                    v4f hv4 = (v4f){hv, hv, hv, hv};
                    #pragma unroll
                    for (int m = 0; m < 16; ++m) yv4[m] += wr4[m] * hv4;
                }
            }
        }
    }

    if (act) {
        #pragma unroll
        for (int k = 0; k < 16; ++k) {
            y[(b*64 + 4*k)*1001 + t]     = yv4[k].x;
            y[(b*64 + 4*k + 1)*1001 + t] = yv4[k].y;
            y[(b*64 + 4*k + 2)*1001 + t] = yv4[k].z;
            y[(b*64 + 4*k + 3)*1001 + t] = yv4[k].w;
        }
    }

    for (int off = 32; off > 0; off >>= 1) hsq += __shfl_down(hsq, off, 64);
    int wid = tid >> 6, lane = tid & 63;
    if (lane == 0) wred[wid] = hsq;
    __syncthreads();
    if (tid == 0) hpart[blockIdx.x] = wred[0] + wred[1] + wred[2] + wred[3];
}

// ---------------------------------------------------------------------------
// pair schedule: round rr, pair j: j==0 -> (63, rr); else
// p=(rr+j)%63, q=(rr+63-j)%63. All pairs disjoint within a round.
__device__ __forceinline__ void pair_pq(int rr, int j, int& p, int& q) {
    if (j == 0) { p = 63; q = rr; }
    else {
        int a = rr + j;       if (a >= 63) a -= 63;
        int c = rr + 63 - j;  if (c >= 63) c -= 63;
        p = a; q = c;
    }
}

union SMu {
    float yt[64][129];                               // syrk staging (33024 B)
    struct { float A[64][65]; float V[64][65]; } j;  // Jacobi (33280 B)
};

__global__ __launch_bounds__(1024) void k_eig(
    const float* __restrict__ y, const float* __restrict__ hpart,
    const float* __restrict__ fcw, const float* __restrict__ fcb,
    float* __restrict__ out)
{
    const int b    = blockIdx.x;
    const int tid  = threadIdx.x;
    const int w    = tid >> 6;     // wave 0..15
    const int lane = tid & 63;

    __shared__ SMu U;
    __shared__ float le[64];
    __shared__ float wred2[16];

    // ---- syrk: acc = y y^T; staging by all 16 waves, MACs on first 256 ----
    const int mg = tid >> 4, ng = tid & 15;       // valid for tid<256
    const int m0 = mg * 4,  n0 = ng * 4;
    float acc[16];
    #pragma unroll
    for (int i = 0; i < 16; ++i) acc[i] = 0.f;
    for (int tile = 0; tile < 8; ++tile) {
        for (int idx = tid; idx < 64*128; idx += 1024) {
            int row = idx >> 7, col = idx & 127;
            int tg = tile * 128 + col;
            U.yt[row][col] = (tg <= 1000) ? y[(b*64 + row)*1001 + tg] : 0.f;
        }
        __syncthreads();
        if (tid < 256) {
            for (int tt = 0; tt < 128; ++tt) {
                float ym[4], yn[4];
                #pragma unroll
                for (int i = 0; i < 4; ++i) ym[i] = U.yt[m0 + i][tt];
                #pragma unroll
                for (int j = 0; j < 4; ++j) yn[j] = U.yt[n0 + j][tt];
                #pragma unroll
                for (int i = 0; i < 4; ++i)
                    #pragma unroll
                    for (int j = 0; j < 4; ++j) acc[i*4 + j] += ym[i] * yn[j];
            }
        }
        __syncthreads();
    }
    if (tid < 256) {
        float hs = hpart[b*4] + hpart[b*4+1] + hpart[b*4+2] + hpart[b*4+3];
        float mu = hs / (999.f * 450.f);
        #pragma unroll
        for (int i = 0; i < 4; ++i)
            #pragma unroll
            for (int j = 0; j < 4; ++j) {
                int mm = m0 + i, nn = n0 + j;
                U.j.A[mm][nn] = acc[i*4 + j] * (0.95f / 999.f)
                              + ((mm == nn) ? 0.05f * mu : 0.f);
                U.j.V[mm][nn] = (mm == nn) ? 1.f : 0.f;
            }
    }
    __syncthreads();

    // ---- parallel cyclic Jacobi: 16 waves x 2 pairs, conflict-free b32 ----
    for (int sweep = 0; sweep < NSWEEP; ++sweep)
    for (int rr = 0; rr < 63; ++rr) {
        float cp, sp;
        {
            int jj = w + ((lane & 1) << 4);
            int p, q; pair_pq(rr, jj, p, q);
            float app = U.j.A[p][p], aqq = U.j.A[q][q], apq = U.j.A[p][q];
            bool z = (fabsf(apq) <= 1e-30f);
            float apqs = z ? 1.f : apq;
            float tau = (aqq - app) * __builtin_amdgcn_rcpf(2.f * apqs);
            float tt = copysignf(1.f, tau) / (fabsf(tau) + sqrtf(1.f + tau*tau));
            float c = rsqrtf(1.f + tt*tt);
            float s = tt * c;
            cp = z ? 1.f : c;
            sp = z ? 0.f : s;
        }
        float c0 = __shfl(cp, 0, 64), s0 = __shfl(sp, 0, 64);
        float c1 = __shfl(cp, 1, 64), s1 = __shfl(sp, 1, 64);
        int p0, q0, p1, q1;
        pair_pq(rr, w,      p0, q0);
        pair_pq(rr, w + 16, p1, q1);

        // col phase: batched loads, rotate, batched stores (A and V)
        float a0p = U.j.A[lane][p0], a0q = U.j.A[lane][q0];
        float a1p = U.j.A[lane][p1], a1q = U.j.A[lane][q1];
        float v0p = U.j.V[lane][p0], v0q = U.j.V[lane][q0];
        float v1p = U.j.V[lane][p1], v1q = U.j.V[lane][q1];
        U.j.A[lane][p0] = c0*a0p - s0*a0q;
        U.j.A[lane][q0] = s0*a0p + c0*a0q;
        U.j.A[lane][p1] = c1*a1p - s1*a1q;
        U.j.A[lane][q1] = s1*a1p + c1*a1q;
        U.j.V[lane][p0] = c0*v0p - s0*v0q;
        U.j.V[lane][q0] = s0*v0p + c0*v0q;
        U.j.V[lane][p1] = c1*v1p - s1*v1q;
        U.j.V[lane][q1] = s1*v1p + c1*v1q;
        __syncthreads();

        // row phase (A only)
        float r0p = U.j.A[p0][lane], r0q = U.j.A[q0][lane];
        float r1p = U.j.A[p1][lane], r1q = U.j.A[q1][lane];
        U.j.A[p0][lane] = c0*r0p - s0*r0q;
        U.j.A[q0][lane] = s0*r0p + c0*r0q;
        U.j.A[p1][lane] = c1*r1p - s1*r1q;
        U.j.A[q1][lane] = s1*r1p + c1*r1q;
        __syncthreads();
    }

    // ---- log-eig reconstruction + FC (first 256 threads) ----
    if (tid < 64) le[tid] = logf(fmaxf(U.j.A[tid][tid], 1e-6f));
    __syncthreads();

    if (tid < 256) {
        float lm[16];
        #pragma unroll
        for (int i = 0; i < 16; ++i) lm[i] = 0.f;
        for (int k = 0; k < 64; ++k) {
            float l = le[k];
            float vm[4], vn[4];
            #pragma unroll
            for (int i = 0; i < 4; ++i) vm[i] = U.j.V[m0 + i][k] * l;
            #pragma unroll
            for (int j = 0; j < 4; ++j) vn[j] = U.j.V[n0 + j][k];
            #pragma unroll
            for (int i = 0; i < 4; ++i)
                #pragma unroll
                for (int j = 0; j < 4; ++j) lm[i*4 + j] += vm[i] * vn[j];
        }

        float fa[4];
        #pragma unroll
        for (int o = 0; o < 4; ++o) fa[o] = 0.f;
        #pragma unroll
        for (int i = 0; i < 4; ++i)
            #pragma unroll
            for (int j = 0; j < 4; ++j) {
                int gi = m0 + i, gj = n0 + j;
                if (gi <= gj) {
                    int p = gi*64 - (gi*(gi-1))/2 + (gj - gi);
                    float lv = lm[i*4 + j];
                    #pragma unroll
                    for (int o = 0; o < 4; ++o) fa[o] += lv * fcw[o*2080 + p];
                }
            }

        #pragma unroll
        for (int o = 0; o < 4; ++o)
            for (int off = 32; off > 0; off >>= 1)
                fa[o] += __shfl_down(fa[o], off, 64);
        if (lane == 0) {
            #pragma unroll
            for (int o = 0; o < 4; ++o) wred2[w*4 + o] = fa[o];
        }
    }
    __syncthreads();
    if (tid < 4)
        out[b*4 + tid] = wred2[tid] + wred2[4 + tid] + wred2[8 + tid]
                       + wred2[12 + tid] + fcb[tid];
}

// ---------------------------------------------------------------------------
extern "C" void kernel_launch(void* const* d_in, const int* in_sizes, int n_in,
                              void* d_out, int out_size, void* d_ws, size_t ws_size,
                              hipStream_t stream) {
    (void)in_sizes; (void)n_in; (void)out_size; (void)ws_size;
    const float* x   = (const float*)d_in[0];
    const float* ws0 = (const float*)d_in[1];
    const float* ws1 = (const float*)d_in[2];
    const float* ws2 = (const float*)d_in[3];
    const float* bsg = (const float*)d_in[4];
    const float* bsb = (const float*)d_in[5];
    const float* bsm = (const float*)d_in[6];
    const float* bsv = (const float*)d_in[7];
    const float* wf  = (const float*)d_in[8];
    const float* bfg = (const float*)d_in[9];
    const float* bfb = (const float*)d_in[10];
    const float* bfm = (const float*)d_in[11];
    const float* bfv = (const float*)d_in[12];
    const float* wt0 = (const float*)d_in[13];
    const float* wt1 = (const float*)d_in[14];
    const float* wt2 = (const float*)d_in[15];
    const float* btg = (const float*)d_in[16];
    const float* btb = (const float*)d_in[17];
    const float* btm = (const float*)d_in[18];
    const float* btv = (const float*)d_in[19];
    const float* Wm  = (const float*)d_in[20];
    const float* fcw = (const float*)d_in[21];
    const float* fcb = (const float*)d_in[22];

    float* wsf   = (float*)d_ws;
    float* yb    = wsf + WS_Y;
    float* hpart = wsf + WS_HPART;

    k_prep<<<1, 512, 0, stream>>>(ws0, ws1, ws2, bsg, bsb, bsm, bsv,
                                  wf, bfg, bfb, bfm, bfv,
                                  wt0, wt1, wt2, btg, btb, btm, btv, wsf);
    k_main<<<512, 256, 0, stream>>>(x, wsf, Wm, yb, hpart);
    k_eig<<<128, 1024, 0, stream>>>(yb, hpart, fcw, fcb, (float*)d_out);
}

// Round 17
// 605.228 us; speedup vs baseline: 1.2893x; 1.1063x over previous
//
#include <hip/hip_runtime.h>
#include <math.h>

// ---------------------------------------------------------------------------
// STaRNet forward, fully fused fp32 pipeline.
//
//  k_prep : fold spatial convs+BN+wf-conv+BN into M(50x22)+biasf(50);
//           fold temporal BN into COMPACT conv taps wtf[50][336] + bt[450].
//  k_main : R13 (measured ~244us): 2-phase g-split, xt[25][320] (31.25KB,
//           5 blocks/CU), v4f conv + y-accum, accumulators in registers.
//  k_eig  : R12 structure verbatim (16 waves x 2 pairs = verified local
//           optimum) with NSWEEP 5->4.  R16 evidence: absmax at 5 sweeps
//           == absmax at 6 sweeps == 2^-9 exactly -> Jacobi truncation is
//           BELOW the pipeline fp32 noise floor at 5; 4 sweeps predicted
//           <= ~4e-3 vs 9.49e-3 threshold.  Rounds 315->252.
// ---------------------------------------------------------------------------

typedef __attribute__((ext_vector_type(4))) float v4f;

#define NSWEEP 4

// ws float offsets
#define WS_M      0         // 50*22
#define WS_BIASF  1100      // 50
#define WS_WTF    1152      // 50*336 compact taps
#define WS_BT     17952     // 450
#define WS_HPART  18432     // 512
#define WS_Y      32768     // 128*64*1001

__global__ void k_prep(
    const float* __restrict__ ws0, const float* __restrict__ ws1, const float* __restrict__ ws2,
    const float* __restrict__ bsg, const float* __restrict__ bsb, const float* __restrict__ bsm, const float* __restrict__ bsv,
    const float* __restrict__ wf,
    const float* __restrict__ bfg, const float* __restrict__ bfb, const float* __restrict__ bfm, const float* __restrict__ bfv,
    const float* __restrict__ wt0, const float* __restrict__ wt1, const float* __restrict__ wt2,
    const float* __restrict__ btg, const float* __restrict__ btb, const float* __restrict__ btm, const float* __restrict__ btv,
    float* __restrict__ wsf)
{
    int tid = threadIdx.x;
    if (tid < 450) {
        int c = tid;
        int i = c / 150, o = c % 150;
        int g = o / 3,   jr = o % 3;
        int k = (i == 0) ? 64 : ((i == 1) ? 32 : 16);
        float ga = btg[i*150 + o], bb = btb[i*150 + o];
        float mm = btm[i*150 + o], vv = btv[i*150 + o];
        float s = ga * rsqrtf(vv + 1e-5f);
        wsf[WS_BT + c] = bb - s * mm;
        int base = g*336 + ((i == 0) ? jr*64 : (i == 1) ? 192 + jr*32 : 288 + jr*16);
        const float* wsrc = (i == 0) ? wt0 : ((i == 1) ? wt1 : wt2);
        float* dst = wsf + WS_WTF + base;
        for (int t = 0; t < k; ++t) dst[t] = s * wsrc[o*k + t];
    }
    if (tid < 50) {
        int f = tid;
        float sf = bfg[f] * rsqrtf(bfv[f] + 1e-5f);
        float row[22];
        for (int c = 0; c < 22; ++c) row[c] = 0.f;
        float bacc = 0.f;
        for (int j = 0; j < 60; ++j) {
            int i, k, j0; const float* wsp;
            if (j < 22)      { i = 0; k = 1; j0 = j;      wsp = ws0; }
            else if (j < 42) { i = 1; k = 3; j0 = j - 22; wsp = ws1; }
            else             { i = 2; k = 5; j0 = j - 42; wsp = ws2; }
            float si = bsg[i] * rsqrtf(bsv[i] + 1e-5f);
            float bi = bsb[i] - si * bsm[i];
            float wfj = wf[f*60 + j];
            for (int d = 0; d < k; ++d) row[j0 + d] += wfj * si * wsp[d];
            bacc += wfj * bi;
        }
        for (int c = 0; c < 22; ++c) wsf[WS_M + f*22 + c] = sf * row[c];
        wsf[WS_BIASF + f] = sf * (bacc - bfm[f]) + bfb[f];
    }
}

// ---------------------------------------------------------------------------
__global__ __launch_bounds__(256) void k_main(
    const float* __restrict__ x, const float* __restrict__ wsf,
    const float* __restrict__ Wmap, float* __restrict__ y,
    float* __restrict__ hpart)
{
    const int b    = blockIdx.x >> 2;
    const int tile = blockIdx.x & 3;
    const int t0   = tile * 256;
    const int tid  = threadIdx.x;

    __shared__ float xt[25][320];   // xf half-tile (31.25 KB -> 5 blocks/CU)
    __shared__ float wred[4];

    const float* Mg    = wsf + WS_M;
    const float* biasf = wsf + WS_BIASF;
    const float* wtf   = wsf + WS_WTF;
    const float* bt    = wsf + WS_BT;

    const int t = t0 + tid;
    const bool act = (t <= 1000);
    v4f yv4[16];
    #pragma unroll
    for (int m = 0; m < 16; ++m) yv4[m] = (v4f){0.f, 0.f, 0.f, 0.f};
    float hsq = 0.f;

    for (int ph = 0; ph < 2; ++ph) {
        const int gbase = 25 * ph;
        if (ph) __syncthreads();   // prev-phase conv reads done before restage

        // ---- stage xf rows [gbase, gbase+25) ----
        for (int col = tid; col < 320; col += 256) {
            int tx = t0 + col - 32;
            if (tx >= 0 && tx < 1000) {
                float xv[22];
                #pragma unroll
                for (int c = 0; c < 22; ++c) xv[c] = x[(b*22 + c)*1000 + tx];
                for (int gl = 0; gl < 25; ++gl) {
                    int g = gbase + gl;
                    float a = biasf[g];
                    #pragma unroll
                    for (int c = 0; c < 22; ++c) a += Mg[g*22 + c] * xv[c];
                    xt[gl][col] = a;
                }
            } else {
                for (int gl = 0; gl < 25; ++gl) xt[gl][col] = 0.f;
            }
        }
        __syncthreads();

        // ---- conv + y-accum for these 25 g ----
        if (act) {
            for (int gl = 0; gl < 25; ++gl) {
                const int g = gbase + gl;
                const float* xb = &xt[gl][tid];
                const float* wg = wtf + g * 336;
                v4f h4[9];
                #pragma unroll
                for (int j = 0; j < 9; ++j) h4[j] = (v4f){0.f, 0.f, 0.f, 0.f};
                #pragma unroll
                for (int tau = 0; tau < 64; tau += 4) {
                    v4f xv = (v4f){xb[tau], xb[tau+1], xb[tau+2], xb[tau+3]};
                    h4[0] += (*(const v4f*)(wg + tau))       * xv;
                    h4[1] += (*(const v4f*)(wg + 64 + tau))  * xv;
                    h4[2] += (*(const v4f*)(wg + 128 + tau)) * xv;
                    if (tau >= 16 && tau < 48) {
                        int u = tau - 16;
                        h4[3] += (*(const v4f*)(wg + 192 + u)) * xv;
                        h4[4] += (*(const v4f*)(wg + 224 + u)) * xv;
                        h4[5] += (*(const v4f*)(wg + 256 + u)) * xv;
                    }
                    if (tau >= 24 && tau < 40) {
                        int u = tau - 24;
                        h4[6] += (*(const v4f*)(wg + 288 + u)) * xv;
                        h4[7] += (*(const v4f*)(wg + 304 + u)) * xv;
                        h4[8] += (*(const v4f*)(wg + 320 + u)) * xv;
                    }
                }
                #pragma unroll
                for (int j = 0; j < 9; ++j) {
                    int c = (j < 3) ? (3*g + j)
                          : (j < 6) ? (150 + 3*g + (j - 3))
                                    : (300 + 3*g + (j - 6));
                    float hv = (h4[j].x + h4[j].y) + (h4[j].z + h4[j].w) + bt[c];
                    hsq += hv * hv;
                    const v4f* wr4 = (const v4f*)(Wmap + c * 64);  // wave-uniform
                    v4f hv4 = (v4f){hv, hv, hv, hv};
                    #pragma unroll
                    for (int m = 0; m < 16; ++m) yv4[m] += wr4[m] * hv4;
                }
            }
        }
    }

    if (act) {
        #pragma unroll
        for (int k = 0; k < 16; ++k) {
            y[(b*64 + 4*k)*1001 + t]     = yv4[k].x;
            y[(b*64 + 4*k + 1)*1001 + t] = yv4[k].y;
            y[(b*64 + 4*k + 2)*1001 + t] = yv4[k].z;
            y[(b*64 + 4*k + 3)*1001 + t] = yv4[k].w;
        }
    }

    for (int off = 32; off > 0; off >>= 1) hsq += __shfl_down(hsq, off, 64);
    int wid = tid >> 6, lane = tid & 63;
    if (lane == 0) wred[wid] = hsq;
    __syncthreads();
    if (tid == 0) hpart[blockIdx.x] = wred[0] + wred[1] + wred[2] + wred[3];
}

// ---------------------------------------------------------------------------
// pair schedule: round rr, pair j: j==0 -> (63, rr); else
// p=(rr+j)%63, q=(rr+63-j)%63. All pairs disjoint within a round.
__device__ __forceinline__ void pair_pq(int rr, int j, int& p, int& q) {
    if (j == 0) { p = 63; q = rr; }
    else {
        int a = rr + j;       if (a >= 63) a -= 63;
        int c = rr + 63 - j;  if (c >= 63) c -= 63;
        p = a; q = c;
    }
}

union SMu {
    float yt[64][129];                               // syrk staging (33024 B)
    struct { float A[64][65]; float V[64][65]; } j;  // Jacobi (33280 B)
};

__global__ __launch_bounds__(1024) void k_eig(
    const float* __restrict__ y, const float* __restrict__ hpart,
    const float* __restrict__ fcw, const float* __restrict__ fcb,
    float* __restrict__ out)
{
    const int b    = blockIdx.x;
    const int tid  = threadIdx.x;
    const int w    = tid >> 6;     // wave 0..15
    const int lane = tid & 63;

    __shared__ SMu U;
    __shared__ float le[64];
    __shared__ float wred2[16];

    // ---- syrk: acc = y y^T; staging by all 16 waves, MACs on first 256 ----
    const int mg = tid >> 4, ng = tid & 15;       // valid for tid<256
    const int m0 = mg * 4,  n0 = ng * 4;
    float acc[16];
    #pragma unroll
    for (int i = 0; i < 16; ++i) acc[i] = 0.f;
    for (int tile = 0; tile < 8; ++tile) {
        for (int idx = tid; idx < 64*128; idx += 1024) {
            int row = idx >> 7, col = idx & 127;
            int tg = tile * 128 + col;
            U.yt[row][col] = (tg <= 1000) ? y[(b*64 + row)*1001 + tg] : 0.f;
        }
        __syncthreads();
        if (tid < 256) {
            for (int tt = 0; tt < 128; ++tt) {
                float ym[4], yn[4];
                #pragma unroll
                for (int i = 0; i < 4; ++i) ym[i] = U.yt[m0 + i][tt];
                #pragma unroll
                for (int j = 0; j < 4; ++j) yn[j] = U.yt[n0 + j][tt];
                #pragma unroll
                for (int i = 0; i < 4; ++i)
                    #pragma unroll
                    for (int j = 0; j < 4; ++j) acc[i*4 + j] += ym[i] * yn[j];
            }
        }
        __syncthreads();
    }
    if (tid < 256) {
        float hs = hpart[b*4] + hpart[b*4+1] + hpart[b*4+2] + hpart[b*4+3];
        float mu = hs / (999.f * 450.f);
        #pragma unroll
        for (int i = 0; i < 4; ++i)
            #pragma unroll
            for (int j = 0; j < 4; ++j) {
                int mm = m0 + i, nn = n0 + j;
                U.j.A[mm][nn] = acc[i*4 + j] * (0.95f / 999.f)
                              + ((mm == nn) ? 0.05f * mu : 0.f);
                U.j.V[mm][nn] = (mm == nn) ? 1.f : 0.f;
            }
    }
    __syncthreads();

    // ---- parallel cyclic Jacobi: 16 waves x 2 pairs, conflict-free b32 ----
    for (int sweep = 0; sweep < NSWEEP; ++sweep)
    for (int rr = 0; rr < 63; ++rr) {
        float cp, sp;
        {
            int jj = w + ((lane & 1) << 4);
            int p, q; pair_pq(rr, jj, p, q);
            float app = U.j.A[p][p], aqq = U.j.A[q][q], apq = U.j.A[p][q];
            bool z = (fabsf(apq) <= 1e-30f);
            float apqs = z ? 1.f : apq;
            float tau = (aqq - app) * __builtin_amdgcn_rcpf(2.f * apqs);
            float tt = copysignf(1.f, tau) / (fabsf(tau) + sqrtf(1.f + tau*tau));
            float c = rsqrtf(1.f + tt*tt);
            float s = tt * c;
            cp = z ? 1.f : c;
            sp = z ? 0.f : s;
        }
        float c0 = __shfl(cp, 0, 64), s0 = __shfl(sp, 0, 64);
        float c1 = __shfl(cp, 1, 64), s1 = __shfl(sp, 1, 64);
        int p0, q0, p1, q1;
        pair_pq(rr, w,      p0, q0);
        pair_pq(rr, w + 16, p1, q1);

        // col phase: batched loads, rotate, batched stores (A and V)
        float a0p = U.j.A[lane][p0], a0q = U.j.A[lane][q0];
        float a1p = U.j.A[lane][p1], a1q = U.j.A[lane][q1];
        float v0p = U.j.V[lane][p0], v0q = U.j.V[lane][q0];
        float v1p = U.j.V[lane][p1], v1q = U.j.V[lane][q1];
        U.j.A[lane][p0] = c0*a0p - s0*a0q;
        U.j.A[lane][q0] = s0*a0p + c0*a0q;
        U.j.A[lane][p1] = c1*a1p - s1*a1q;
        U.j.A[lane][q1] = s1*a1p + c1*a1q;
        U.j.V[lane][p0] = c0*v0p - s0*v0q;
        U.j.V[lane][q0] = s0*v0p + c0*v0q;
        U.j.V[lane][p1] = c1*v1p - s1*v1q;
        U.j.V[lane][q1] = s1*v1p + c1*v1q;
        __syncthreads();

        // row phase (A only)
        float r0p = U.j.A[p0][lane], r0q = U.j.A[q0][lane];
        float r1p = U.j.A[p1][lane], r1q = U.j.A[q1][lane];
        U.j.A[p0][lane] = c0*r0p - s0*r0q;
        U.j.A[q0][lane] = s0*r0p + c0*r0q;
        U.j.A[p1][lane] = c1*r1p - s1*r1q;
        U.j.A[q1][lane] = s1*r1p + c1*r1q;
        __syncthreads();
    }

    // ---- log-eig reconstruction + FC (first 256 threads) ----
    if (tid < 64) le[tid] = logf(fmaxf(U.j.A[tid][tid], 1e-6f));
    __syncthreads();

    if (tid < 256) {
        float lm[16];
        #pragma unroll
        for (int i = 0; i < 16; ++i) lm[i] = 0.f;
        for (int k = 0; k < 64; ++k) {
            float l = le[k];
            float vm[4], vn[4];
            #pragma unroll
            for (int i = 0; i < 4; ++i) vm[i] = U.j.V[m0 + i][k] * l;
            #pragma unroll
            for (int j = 0; j < 4; ++j) vn[j] = U.j.V[n0 + j][k];
            #pragma unroll
            for (int i = 0; i < 4; ++i)
                #pragma unroll
                for (int j = 0; j < 4; ++j) lm[i*4 + j] += vm[i] * vn[j];
        }

        float fa[4];
        #pragma unroll
        for (int o = 0; o < 4; ++o) fa[o] = 0.f;
        #pragma unroll
        for (int i = 0; i < 4; ++i)
            #pragma unroll
            for (int j = 0; j < 4; ++j) {
                int gi = m0 + i, gj = n0 + j;
                if (gi <= gj) {
                    int p = gi*64 - (gi*(gi-1))/2 + (gj - gi);
                    float lv = lm[i*4 + j];
                    #pragma unroll
                    for (int o = 0; o < 4; ++o) fa[o] += lv * fcw[o*2080 + p];
                }
            }

        #pragma unroll
        for (int o = 0; o < 4; ++o)
            for (int off = 32; off > 0; off >>= 1)
                fa[o] += __shfl_down(fa[o], off, 64);
        if (lane == 0) {
            #pragma unroll
            for (int o = 0; o < 4; ++o) wred2[w*4 + o] = fa[o];
        }
    }
    __syncthreads();
    if (tid < 4)
        out[b*4 + tid] = wred2[tid] + wred2[4 + tid] + wred2[8 + tid]
                       + wred2[12 + tid] + fcb[tid];
}

// ---------------------------------------------------------------------------
extern "C" void kernel_launch(void* const* d_in, const int* in_sizes, int n_in,
                              void* d_out, int out_size, void* d_ws, size_t ws_size,
                              hipStream_t stream) {
    (void)in_sizes; (void)n_in; (void)out_size; (void)ws_size;
    const float* x   = (const float*)d_in[0];
    const float* ws0 = (const float*)d_in[1];
    const float* ws1 = (const float*)d_in[2];
    const float* ws2 = (const float*)d_in[3];
    const float* bsg = (const float*)d_in[4];
    const float* bsb = (const float*)d_in[5];
    const float* bsm = (const float*)d_in[6];
    const float* bsv = (const float*)d_in[7];
    const float* wf  = (const float*)d_in[8];
    const float* bfg = (const float*)d_in[9];
    const float* bfb = (const float*)d_in[10];
    const float* bfm = (const float*)d_in[11];
    const float* bfv = (const float*)d_in[12];
    const float* wt0 = (const float*)d_in[13];
    const float* wt1 = (const float*)d_in[14];
    const float* wt2 = (const float*)d_in[15];
    const float* btg = (const float*)d_in[16];
    const float* btb = (const float*)d_in[17];
    const float* btm = (const float*)d_in[18];
    const float* btv = (const float*)d_in[19];
    const float* Wm  = (const float*)d_in[20];
    const float* fcw = (const float*)d_in[21];
    const float* fcb = (const float*)d_in[22];

    float* wsf   = (float*)d_ws;
    float* yb    = wsf + WS_Y;
    float* hpart = wsf + WS_HPART;

    k_prep<<<1, 512, 0, stream>>>(ws0, ws1, ws2, bsg, bsb, bsm, bsv,
                                  wf, bfg, bfb, bfm, bfv,
                                  wt0, wt1, wt2, btg, btb, btm, btv, wsf);
    k_main<<<512, 256, 0, stream>>>(x, wsf, Wm, yb, hpart);
    k_eig<<<128, 1024, 0, stream>>>(yb, hpart, fcw, fcb, (float*)d_out);
}

// Round 18
// 600.598 us; speedup vs baseline: 1.2993x; 1.0077x over previous
//
#include <hip/hip_runtime.h>
#include <math.h>

// ---------------------------------------------------------------------------
// STaRNet forward, fully fused fp32 pipeline.
//
//  k_prep : fold spatial convs+BN+wf-conv+BN into M(50x22)+biasf(50);
//           fold temporal BN into COMPACT conv taps wtf[50][336] + bt[450].
//  k_main : R13 (measured ~244us): 2-phase g-split, xt[25][320] (31.25KB,
//           5 blocks/CU), v4f conv + y-accum, accumulators in registers.
//  k_eig  : R12 structure verbatim (16 waves x 2 pairs = verified local
//           optimum) with NSWEEP 5->4.  R16 evidence: absmax at 5 sweeps
//           == absmax at 6 sweeps == 2^-9 exactly -> Jacobi truncation is
//           BELOW the pipeline fp32 noise floor at 5; 4 sweeps predicted
//           <= ~4e-3 vs 9.49e-3 threshold.  Rounds 315->252.
// ---------------------------------------------------------------------------

typedef __attribute__((ext_vector_type(4))) float v4f;

#define NSWEEP 4

// ws float offsets
#define WS_M      0         // 50*22
#define WS_BIASF  1100      // 50
#define WS_WTF    1152      // 50*336 compact taps
#define WS_BT     17952     // 450
#define WS_HPART  18432     // 512
#define WS_Y      32768     // 128*64*1001

__global__ void k_prep(
    const float* __restrict__ ws0, const float* __restrict__ ws1, const float* __restrict__ ws2,
    const float* __restrict__ bsg, const float* __restrict__ bsb, const float* __restrict__ bsm, const float* __restrict__ bsv,
    const float* __restrict__ wf,
    const float* __restrict__ bfg, const float* __restrict__ bfb, const float* __restrict__ bfm, const float* __restrict__ bfv,
    const float* __restrict__ wt0, const float* __restrict__ wt1, const float* __restrict__ wt2,
    const float* __restrict__ btg, const float* __restrict__ btb, const float* __restrict__ btm, const float* __restrict__ btv,
    float* __restrict__ wsf)
{
    int tid = threadIdx.x;
    if (tid < 450) {
        int c = tid;
        int i = c / 150, o = c % 150;
        int g = o / 3,   jr = o % 3;
        int k = (i == 0) ? 64 : ((i == 1) ? 32 : 16);
        float ga = btg[i*150 + o], bb = btb[i*150 + o];
        float mm = btm[i*150 + o], vv = btv[i*150 + o];
        float s = ga * rsqrtf(vv + 1e-5f);
        wsf[WS_BT + c] = bb - s * mm;
        int base = g*336 + ((i == 0) ? jr*64 : (i == 1) ? 192 + jr*32 : 288 + jr*16);
        const float* wsrc = (i == 0) ? wt0 : ((i == 1) ? wt1 : wt2);
        float* dst = wsf + WS_WTF + base;
        for (int t = 0; t < k; ++t) dst[t] = s * wsrc[o*k + t];
    }
    if (tid < 50) {
        int f = tid;
        float sf = bfg[f] * rsqrtf(bfv[f] + 1e-5f);
        float row[22];
        for (int c = 0; c < 22; ++c) row[c] = 0.f;
        float bacc = 0.f;
        for (int j = 0; j < 60; ++j) {
            int i, k, j0; const float* wsp;
            if (j < 22)      { i = 0; k = 1; j0 = j;      wsp = ws0; }
            else if (j < 42) { i = 1; k = 3; j0 = j - 22; wsp = ws1; }
            else             { i = 2; k = 5; j0 = j - 42; wsp = ws2; }
            float si = bsg[i] * rsqrtf(bsv[i] + 1e-5f);
            float bi = bsb[i] - si * bsm[i];
            float wfj = wf[f*60 + j];
            for (int d = 0; d < k; ++d) row[j0 + d] += wfj * si * wsp[d];
            bacc += wfj * bi;
        }
        for (int c = 0; c < 22; ++c) wsf[WS_M + f*22 + c] = sf * row[c];
        wsf[WS_BIASF + f] = sf * (bacc - bfm[f]) + bfb[f];
    }
}

// ---------------------------------------------------------------------------
__global__ __launch_bounds__(256) void k_main(
    const float* __restrict__ x, const float* __restrict__ wsf,
    const float* __restrict__ Wmap, float* __restrict__ y,
    float* __restrict__ hpart)
{
    const int b    = blockIdx.x >> 2;
    const int tile = blockIdx.x & 3;
    const int t0   = tile * 256;
    const int tid  = threadIdx.x;

    __shared__ float xt[25][320];   // xf half-tile (31.25 KB -> 5 blocks/CU)
    __shared__ float wred[4];

    const float* Mg    = wsf + WS_M;
    const float* biasf = wsf + WS_BIASF;
    const float* wtf   = wsf + WS_WTF;
    const float* bt    = wsf + WS_BT;

    const int t = t0 + tid;
    const bool act = (t <= 1000);
    v4f yv4[16];
    #pragma unroll
    for (int m = 0; m < 16; ++m) yv4[m] = (v4f){0.f, 0.f, 0.f, 0.f};
    float hsq = 0.f;

    for (int ph = 0; ph < 2; ++ph) {
        const int gbase = 25 * ph;
        if (ph) __syncthreads();   // prev-phase conv reads done before restage

        // ---- stage xf rows [gbase, gbase+25) ----
        for (int col = tid; col < 320; col += 256) {
            int tx = t0 + col - 32;
            if (tx >= 0 && tx < 1000) {
                float xv[22];
                #pragma unroll
                for (int c = 0; c < 22; ++c) xv[c] = x[(b*22 + c)*1000 + tx];
                for (int gl = 0; gl < 25; ++gl) {
                    int g = gbase + gl;
                    float a = biasf[g];
                    #pragma unroll
                    for (int c = 0; c < 22; ++c) a += Mg[g*22 + c] * xv[c];
                    xt[gl][col] = a;
                }
            } else {
                for (int gl = 0; gl < 25; ++gl) xt[gl][col] = 0.f;
            }
        }
        __syncthreads();

        // ---- conv + y-accum for these 25 g ----
        if (act) {
            for (int gl = 0; gl < 25; ++gl) {
                const int g = gbase + gl;
                const float* xb = &xt[gl][tid];
                const float* wg = wtf + g * 336;
                v4f h4[9];
                #pragma unroll
                for (int j = 0; j < 9; ++j) h4[j] = (v4f){0.f, 0.f, 0.f, 0.f};
                #pragma unroll
                for (int tau = 0; tau < 64; tau += 4) {
                    v4f xv = (v4f){xb[tau], xb[tau+1], xb[tau+2], xb[tau+3]};
                    h4[0] += (*(const v4f*)(wg + tau))       * xv;
                    h4[1] += (*(const v4f*)(wg + 64 + tau))  * xv;
                    h4[2] += (*(const v4f*)(wg + 128 + tau)) * xv;
                    if (tau >= 16 && tau < 48) {
                        int u = tau - 16;
                        h4[3] += (*(const v4f*)(wg + 192 + u)) * xv;
                        h4[4] += (*(const v4f*)(wg + 224 + u)) * xv;
                        h4[5] += (*(const v4f*)(wg + 256 + u)) * xv;
                    }
                    if (tau >= 24 && tau < 40) {
                        int u = tau - 24;
                        h4[6] += (*(const v4f*)(wg + 288 + u)) * xv;
                        h4[7] += (*(const v4f*)(wg + 304 + u)) * xv;
                        h4[8] += (*(const v4f*)(wg + 320 + u)) * xv;
                    }
                }
                #pragma unroll
                for (int j = 0; j < 9; ++j) {
                    int c = (j < 3) ? (3*g + j)
                          : (j < 6) ? (150 + 3*g + (j - 3))
                                    : (300 + 3*g + (j - 6));
                    float hv = (h4[j].x + h4[j].y) + (h4[j].z + h4[j].w) + bt[c];
                    hsq += hv * hv;
                    const v4f* wr4 = (const v4f*)(Wmap + c * 64);  // wave-uniform
                    v4f hv4 = (v4f){hv, hv, hv, hv};
                    #pragma unroll
                    for (int m = 0; m < 16; ++m) yv4[m] += wr4[m] * hv4;
                }
            }
        }
    }

    if (act) {
        #pragma unroll
        for (int k = 0; k < 16; ++k) {
            y[(b*64 + 4*k)*1001 + t]     = yv4[k].x;
            y[(b*64 + 4*k + 1)*1001 + t] = yv4[k].y;
            y[(b*64 + 4*k + 2)*1001 + t] = yv4[k].z;
            y[(b*64 + 4*k + 3)*1001 + t] = yv4[k].w;
        }
    }

    for (int off = 32; off > 0; off >>= 1) hsq += __shfl_down(hsq, off, 64);
    int wid = tid >> 6, lane = tid & 63;
    if (lane == 0) wred[wid] = hsq;
    __syncthreads();
    if (tid == 0) hpart[blockIdx.x] = wred[0] + wred[1] + wred[2] + wred[3];
}

// ---------------------------------------------------------------------------
// pair schedule: round rr, pair j: j==0 -> (63, rr); else
// p=(rr+j)%63, q=(rr+63-j)%63. All pairs disjoint within a round.
__device__ __forceinline__ void pair_pq(int rr, int j, int& p, int& q) {
    if (j == 0) { p = 63; q = rr; }
    else {
        int a = rr + j;       if (a >= 63) a -= 63;
        int c = rr + 63 - j;  if (c >= 63) c -= 63;
        p = a; q = c;
    }
}

union SMu {
    float yt[64][129];                               // syrk staging (33024 B)
    struct { float A[64][65]; float V[64][65]; } j;  // Jacobi (33280 B)
};

__global__ __launch_bounds__(1024) void k_eig(
    const float* __restrict__ y, const float* __restrict__ hpart,
    const float* __restrict__ fcw, const float* __restrict__ fcb,
    float* __restrict__ out)
{
    const int b    = blockIdx.x;
    const int tid  = threadIdx.x;
    const int w    = tid >> 6;     // wave 0..15
    const int lane = tid & 63;

    __shared__ SMu U;
    __shared__ float le[64];
    __shared__ float wred2[16];

    // ---- syrk: acc = y y^T; staging by all 16 waves, MACs on first 256 ----
    const int mg = tid >> 4, ng = tid & 15;       // valid for tid<256
    const int m0 = mg * 4,  n0 = ng * 4;
    float acc[16];
    #pragma unroll
    for (int i = 0; i < 16; ++i) acc[i] = 0.f;
    for (int tile = 0; tile < 8; ++tile) {
        for (int idx = tid; idx < 64*128; idx += 1024) {
            int row = idx >> 7, col = idx & 127;
            int tg = tile * 128 + col;
            U.yt[row][col] = (tg <= 1000) ? y[(b*64 + row)*1001 + tg] : 0.f;
        }
        __syncthreads();
        if (tid < 256) {
            for (int tt = 0; tt < 128; ++tt) {
                float ym[4], yn[4];
                #pragma unroll
                for (int i = 0; i < 4; ++i) ym[i] = U.yt[m0 + i][tt];
                #pragma unroll
                for (int j = 0; j < 4; ++j) yn[j] = U.yt[n0 + j][tt];
                #pragma unroll
                for (int i = 0; i < 4; ++i)
                    #pragma unroll
                    for (int j = 0; j < 4; ++j) acc[i*4 + j] += ym[i] * yn[j];
            }
        }
        __syncthreads();
    }
    if (tid < 256) {
        float hs = hpart[b*4] + hpart[b*4+1] + hpart[b*4+2] + hpart[b*4+3];
        float mu = hs / (999.f * 450.f);
        #pragma unroll
        for (int i = 0; i < 4; ++i)
            #pragma unroll
            for (int j = 0; j < 4; ++j) {
                int mm = m0 + i, nn = n0 + j;
                U.j.A[mm][nn] = acc[i*4 + j] * (0.95f / 999.f)
                              + ((mm == nn) ? 0.05f * mu : 0.f);
                U.j.V[mm][nn] = (mm == nn) ? 1.f : 0.f;
            }
    }
    __syncthreads();

    // ---- parallel cyclic Jacobi: 16 waves x 2 pairs, conflict-free b32 ----
    for (int sweep = 0; sweep < NSWEEP; ++sweep)
    for (int rr = 0; rr < 63; ++rr) {
        float cp, sp;
        {
            int jj = w + ((lane & 1) << 4);
            int p, q; pair_pq(rr, jj, p, q);
            float app = U.j.A[p][p], aqq = U.j.A[q][q], apq = U.j.A[p][q];
            bool z = (fabsf(apq) <= 1e-30f);
            float apqs = z ? 1.f : apq;
            float tau = (aqq - app) * __builtin_amdgcn_rcpf(2.f * apqs);
            float tt = copysignf(1.f, tau) / (fabsf(tau) + sqrtf(1.f + tau*tau));
            float c = rsqrtf(1.f + tt*tt);
            float s = tt * c;
            cp = z ? 1.f : c;
            sp = z ? 0.f : s;
        }
        float c0 = __shfl(cp, 0, 64), s0 = __shfl(sp, 0, 64);
        float c1 = __shfl(cp, 1, 64), s1 = __shfl(sp, 1, 64);
        int p0, q0, p1, q1;
        pair_pq(rr, w,      p0, q0);
        pair_pq(rr, w + 16, p1, q1);

        // col phase: batched loads, rotate, batched stores (A and V)
        float a0p = U.j.A[lane][p0], a0q = U.j.A[lane][q0];
        float a1p = U.j.A[lane][p1], a1q = U.j.A[lane][q1];
        float v0p = U.j.V[lane][p0], v0q = U.j.V[lane][q0];
        float v1p = U.j.V[lane][p1], v1q = U.j.V[lane][q1];
        U.j.A[lane][p0] = c0*a0p - s0*a0q;
        U.j.A[lane][q0] = s0*a0p + c0*a0q;
        U.j.A[lane][p1] = c1*a1p - s1*a1q;
        U.j.A[lane][q1] = s1*a1p + c1*a1q;
        U.j.V[lane][p0] = c0*v0p - s0*v0q;
        U.j.V[lane][q0] = s0*v0p + c0*v0q;
        U.j.V[lane][p1] = c1*v1p - s1*v1q;
        U.j.V[lane][q1] = s1*v1p + c1*v1q;
        __syncthreads();

        // row phase (A only)
        float r0p = U.j.A[p0][lane], r0q = U.j.A[q0][lane];
        float r1p = U.j.A[p1][lane], r1q = U.j.A[q1][lane];
        U.j.A[p0][lane] = c0*r0p - s0*r0q;
        U.j.A[q0][lane] = s0*r0p + c0*r0q;
        U.j.A[p1][lane] = c1*r1p - s1*r1q;
        U.j.A[q1][lane] = s1*r1p + c1*r1q;
        __syncthreads();
    }

    // ---- log-eig reconstruction + FC (first 256 threads) ----
    if (tid < 64) le[tid] = logf(fmaxf(U.j.A[tid][tid], 1e-6f));
    __syncthreads();

    if (tid < 256) {
        float lm[16];
        #pragma unroll
        for (int i = 0; i < 16; ++i) lm[i] = 0.f;
        for (int k = 0; k < 64; ++k) {
            float l = le[k];
            float vm[4], vn[4];
            #pragma unroll
            for (int i = 0; i < 4; ++i) vm[i] = U.j.V[m0 + i][k] * l;
            #pragma unroll
            for (int j = 0; j < 4; ++j) vn[j] = U.j.V[n0 + j][k];
            #pragma unroll
            for (int i = 0; i < 4; ++i)
                #pragma unroll
                for (int j = 0; j < 4; ++j) lm[i*4 + j] += vm[i] * vn[j];
        }

        float fa[4];
        #pragma unroll
        for (int o = 0; o < 4; ++o) fa[o] = 0.f;
        #pragma unroll
        for (int i = 0; i < 4; ++i)
            #pragma unroll
            for (int j = 0; j < 4; ++j) {
                int gi = m0 + i, gj = n0 + j;
                if (gi <= gj) {
                    int p = gi*64 - (gi*(gi-1))/2 + (gj - gi);
                    float lv = lm[i*4 + j];
                    #pragma unroll
                    for (int o = 0; o < 4; ++o) fa[o] += lv * fcw[o*2080 + p];
                }
            }

        #pragma unroll
        for (int o = 0; o < 4; ++o)
            for (int off = 32; off > 0; off >>= 1)
                fa[o] += __shfl_down(fa[o], off, 64);
        if (lane == 0) {
            #pragma unroll
            for (int o = 0; o < 4; ++o) wred2[w*4 + o] = fa[o];
        }
    }
    __syncthreads();
    if (tid < 4)
        out[b*4 + tid] = wred2[tid] + wred2[4 + tid] + wred2[8 + tid]
                       + wred2[12 + tid] + fcb[tid];
}

// ---------------------------------------------------------------------------
extern "C" void kernel_launch(void* const* d_in, const int* in_sizes, int n_in,
                              void* d_out, int out_size, void* d_ws, size_t ws_size,
                              hipStream_t stream) {
    (void)in_sizes; (void)n_in; (void)out_size; (void)ws_size;
    const float* x   = (const float*)d_in[0];
    const float* ws0 = (const float*)d_in[1];
    const float* ws1 = (const float*)d_in[2];
    const float* ws2 = (const float*)d_in[3];
    const float* bsg = (const float*)d_in[4];
    const float* bsb = (const float*)d_in[5];
    const float* bsm = (const float*)d_in[6];
    const float* bsv = (const float*)d_in[7];
    const float* wf  = (const float*)d_in[8];
    const float* bfg = (const float*)d_in[9];
    const float* bfb = (const float*)d_in[10];
    const float* bfm = (const float*)d_in[11];
    const float* bfv = (const float*)d_in[12];
    const float* wt0 = (const float*)d_in[13];
    const float* wt1 = (const float*)d_in[14];
    const float* wt2 = (const float*)d_in[15];
    const float* btg = (const float*)d_in[16];
    const float* btb = (const float*)d_in[17];
    const float* btm = (const float*)d_in[18];
    const float* btv = (const float*)d_in[19];
    const float* Wm  = (const float*)d_in[20];
    const float* fcw = (const float*)d_in[21];
    const float* fcb = (const float*)d_in[22];

    float* wsf   = (float*)d_ws;
    float* yb    = wsf + WS_Y;
    float* hpart = wsf + WS_HPART;

    k_prep<<<1, 512, 0, stream>>>(ws0, ws1, ws2, bsg, bsb, bsm, bsv,
                                  wf, bfg, bfb, bfm, bfv,
                                  wt0, wt1, wt2, btg, btb, btm, btv, wsf);
    k_main<<<512, 256, 0, stream>>>(x, wsf, Wm, yb, hpart);
    k_eig<<<128, 1024, 0, stream>>>(yb, hpart, fcw, fcb, (float*)d_out);
}